// Round 15
// baseline (260.363 us; speedup 1.0000x reference)
//
#include <hip/hip_runtime.h>
#include <hip/hip_bf16.h>

#define KC   1024
#define DD   256
#define NN   32768
#define HWC  1024
#define LOSS_OFF 8388608
#define IDX_OFF  8388609
#define CBT_OFF  2000000   // cbT[256][1024] in out's x_q region; gather overwrites later

// Replicate numpy pairwise_sum of a[i]*a[i], n=256 (validated: absmax 0.0 r2..r14).
__device__ __forceinline__ float np_pairwise_sumsq_256(const float* __restrict__ a) {
#pragma clang fp contract(off)
  float half0, half1;
  {
    const float* p = a;
    float r[8];
#pragma unroll
    for (int j = 0; j < 8; ++j) r[j] = p[j] * p[j];
    for (int i = 8; i < 128; i += 8) {
#pragma unroll
      for (int j = 0; j < 8; ++j) r[j] = r[j] + p[i + j] * p[i + j];
    }
    half0 = ((r[0] + r[1]) + (r[2] + r[3])) + ((r[4] + r[5]) + (r[6] + r[7]));
  }
  {
    const float* p = a + 128;
    float r[8];
#pragma unroll
    for (int j = 0; j < 8; ++j) r[j] = p[j] * p[j];
    for (int i = 8; i < 128; i += 8) {
#pragma unroll
      for (int j = 0; j < 8; ++j) r[j] = r[j] + p[i + j] * p[i + j];
    }
    half1 = ((r[0] + r[1]) + (r[2] + r[3])) + ((r[4] + r[5]) + (r[6] + r[7]));
  }
  return half0 + half1;
}

// K0: e_sq[k] via numpy-pairwise; zero loss accumulator.
__global__ void vq_esq_kernel(const float* __restrict__ cb, float* __restrict__ esq,
                              float* __restrict__ loss_acc) {
  const int k = blockIdx.x * 256 + threadIdx.x;
  if (k == 0) loss_acc[0] = 0.0f;
  if (k < KC) esq[k] = np_pairwise_sumsq_256(cb + ((size_t)k << 8));
}

// K0b: cbT[d][k] = cb[k][d] (1MB, L2-resident; makes argmin e-loads coalesced).
__global__ __launch_bounds__(256) void vq_transpose_kernel(const float* __restrict__ cb,
                                                           float* __restrict__ cbT) {
  const int d = blockIdx.x;     // 0..255
  const int t = threadIdx.x;
#pragma unroll
  for (int q = 0; q < 4; ++q) {
    const int k = (q << 8) + t;
    cbT[(d << 10) + k] = cb[((size_t)k << 8) + d];
  }
}

// K1: fused distance + argmin — r13's structure (best measured, 240us) with the
// e-stream ALSO double-buffered (r13 prefetched only x). Discriminating
// experiment: r11 (ILP on LDS-x base) nulled via occupancy loss; here VGPR
// headroom is 68 -> ~140 of a 256 budget, no squeeze (demand << LB(256,2) cap).
//   wave w: ws=w&1 -> code half [ws*512,+512); rh=w>>1 -> rows rh*8..+8
//   thread: 8 contiguous codes c0 = ws*512 + lane*8; acc[8][8].
//   x via wave-uniform s_load_dwordx8 (SGPRs, dbuf); e via coalesced float4
//   (VGPRs, NOW dbuf'd one chunk ahead).
// FMA chain order byte-identical to r13 (dims ascending, chunk-major).
__global__ __launch_bounds__(256, 2)
void vq_argmin_kernel(const float* __restrict__ x, const float* __restrict__ cbT,
                      const float* __restrict__ esq, int* __restrict__ idxout,
                      float* __restrict__ out) {
  __shared__ float xs[16][260];    // only for the xsq pairwise computation
  __shared__ float xsq[16];
  __shared__ float rbest[4][16];
  __shared__ int   rbidx[4][16];

  const int tid  = threadIdx.x;
  const int lane = tid & 63;
  const int w    = __builtin_amdgcn_readfirstlane(tid >> 6);  // 0..3, SGPR
  const int ws   = w & 1;             // code half
  const int rh   = w >> 1;            // row half
  const int n0   = blockIdx.x << 4;   // 2048 blocks x 16 rows
  const int b    = n0 >> 10;
  const int hw0  = n0 & 1023;
  const float* __restrict__ xb = x + (size_t)b * (DD * HWC) + hw0;

  // Stage x tile for xsq: xs[r][d] = x[b, d, hw0+r].
  {
    const int rr = tid & 15;
    const int dq = tid >> 4;
#pragma unroll
    for (int i = 0; i < 16; ++i) {
      const int d = (i << 4) + dq;
      xs[rr][d] = xb[(size_t)d * HWC + rr];
    }
  }
  __syncthreads();

  // x_sq per row, numpy-pairwise bitwise (tie reproduction — do not change).
  if (tid < 16) xsq[tid] = np_pairwise_sumsq_256(&xs[tid][0]);
  __syncthreads();

  const int c0 = (ws << 9) + (lane << 3);          // 8 contiguous codes
  const int r0 = rh << 3;                          // uniform (w is SGPR)
  const float* __restrict__ xru = xb + r0;         // wave-uniform base

  float acc[8][8];                                 // [code j][row r]
#pragma unroll
  for (int j = 0; j < 8; ++j)
#pragma unroll
    for (int r = 0; r < 8; ++r) acc[j][r] = 0.0f;

// Wave-uniform x loads: XA[di][r] = x[b][dbase+di][hw0+r0+r] (s_load_dwordx8).
#define LOADX(XA, CH)                                                         \
  {                                                                           \
    const int db_ = (CH) << 2;                                                \
    _Pragma("unroll")                                                         \
    for (int di = 0; di < 4; ++di) {                                          \
      const float* __restrict__ rp_ = xru + (size_t)(db_ + di) * HWC;         \
      _Pragma("unroll")                                                       \
      for (int r = 0; r < 8; ++r) XA[di][r] = rp_[r];                         \
    }                                                                         \
  }

// e for chunk CH into EB: EB[di] = codes c0..c0+3 at dim dbase+di,
// EB[4+di] = codes c0+4..c0+7 (coalesced float4 pairs).
#define LOADE(EB, CH)                                                         \
  {                                                                           \
    const int db_ = (CH) << 2;                                                \
    _Pragma("unroll")                                                         \
    for (int di = 0; di < 4; ++di) {                                          \
      const float* __restrict__ rp_ = cbT + ((size_t)(db_ + di) << 10) + c0;  \
      EB[di]     = *(const float4*)rp_;                                       \
      EB[4 + di] = *(const float4*)(rp_ + 4);                                 \
    }                                                                         \
  }

// Chain order identical to r13: acc[j] gets dims ascending (di 0..3) per chunk.
#define FMACHUNK(XA, EB)                                                      \
  {                                                                           \
    _Pragma("unroll")                                                         \
    for (int r = 0; r < 8; ++r) {                                             \
      acc[0][r] = fmaf(XA[0][r], EB[0].x, acc[0][r]);                         \
      acc[0][r] = fmaf(XA[1][r], EB[1].x, acc[0][r]);                         \
      acc[0][r] = fmaf(XA[2][r], EB[2].x, acc[0][r]);                         \
      acc[0][r] = fmaf(XA[3][r], EB[3].x, acc[0][r]);                         \
      acc[1][r] = fmaf(XA[0][r], EB[0].y, acc[1][r]);                         \
      acc[1][r] = fmaf(XA[1][r], EB[1].y, acc[1][r]);                         \
      acc[1][r] = fmaf(XA[2][r], EB[2].y, acc[1][r]);                         \
      acc[1][r] = fmaf(XA[3][r], EB[3].y, acc[1][r]);                         \
      acc[2][r] = fmaf(XA[0][r], EB[0].z, acc[2][r]);                         \
      acc[2][r] = fmaf(XA[1][r], EB[1].z, acc[2][r]);                         \
      acc[2][r] = fmaf(XA[2][r], EB[2].z, acc[2][r]);                         \
      acc[2][r] = fmaf(XA[3][r], EB[3].z, acc[2][r]);                         \
      acc[3][r] = fmaf(XA[0][r], EB[0].w, acc[3][r]);                         \
      acc[3][r] = fmaf(XA[1][r], EB[1].w, acc[3][r]);                         \
      acc[3][r] = fmaf(XA[2][r], EB[2].w, acc[3][r]);                         \
      acc[3][r] = fmaf(XA[3][r], EB[3].w, acc[3][r]);                         \
      acc[4][r] = fmaf(XA[0][r], EB[4].x, acc[4][r]);                         \
      acc[4][r] = fmaf(XA[1][r], EB[5].x, acc[4][r]);                         \
      acc[4][r] = fmaf(XA[2][r], EB[6].x, acc[4][r]);                         \
      acc[4][r] = fmaf(XA[3][r], EB[7].x, acc[4][r]);                         \
      acc[5][r] = fmaf(XA[0][r], EB[4].y, acc[5][r]);                         \
      acc[5][r] = fmaf(XA[1][r], EB[5].y, acc[5][r]);                         \
      acc[5][r] = fmaf(XA[2][r], EB[6].y, acc[5][r]);                         \
      acc[5][r] = fmaf(XA[3][r], EB[7].y, acc[5][r]);                         \
      acc[6][r] = fmaf(XA[0][r], EB[4].z, acc[6][r]);                         \
      acc[6][r] = fmaf(XA[1][r], EB[5].z, acc[6][r]);                         \
      acc[6][r] = fmaf(XA[2][r], EB[6].z, acc[6][r]);                         \
      acc[6][r] = fmaf(XA[3][r], EB[7].z, acc[6][r]);                         \
      acc[7][r] = fmaf(XA[0][r], EB[4].w, acc[7][r]);                         \
      acc[7][r] = fmaf(XA[1][r], EB[5].w, acc[7][r]);                         \
      acc[7][r] = fmaf(XA[2][r], EB[6].w, acc[7][r]);                         \
      acc[7][r] = fmaf(XA[3][r], EB[7].w, acc[7][r]);                         \
    }                                                                         \
  }

  float  xa0[4][8], xa1[4][8];
  float4 eb0[8], eb1[8];
  LOADX(xa0, 0)
  LOADE(eb0, 0)
  for (int ch = 0; ch < 64; ch += 2) {
    LOADE(eb1, ch + 1)                 // prefetch next chunk's e AND x before
    LOADX(xa1, ch + 1)                 // consuming the current buffers
    FMACHUNK(xa0, eb0)
    if (ch < 62) { LOADE(eb0, ch + 2) LOADX(xa0, ch + 2) }
    FMACHUNK(xa1, eb1)
  }
#undef LOADX
#undef LOADE
#undef FMACHUNK

  // esq for 8 contiguous codes: two float4 loads.
  float eq[8];
  {
    const float4 e0 = *(const float4*)(esq + c0);
    const float4 e1 = *(const float4*)(esq + c0 + 4);
    eq[0]=e0.x; eq[1]=e0.y; eq[2]=e0.z; eq[3]=e0.w;
    eq[4]=e1.x; eq[5]=e1.y; eq[6]=e1.z; eq[7]=e1.w;
  }

#pragma unroll
  for (int r = 0; r < 8; ++r) {
    const float xq = xsq[r0 + r];
    float v; int ki;
    {
      // Reference rounding: fl(e_sq - fl(2*dot)) then fl(t + x_sq). No FMA here.
#pragma clang fp contract(off)
      v = (eq[0] - 2.0f * acc[0][r]) + xq; ki = c0;   // ascending j, strict <
#pragma unroll
      for (int j = 1; j < 8; ++j) {
        const float dj = (eq[j] - 2.0f * acc[j][r]) + xq;
        if (dj < v) { v = dj; ki = c0 + j; }
      }
    }
    // Wave-wide (val,idx) min, lowest k on ties.
#pragma unroll
    for (int off = 32; off >= 1; off >>= 1) {
      const float v2 = __shfl_xor(v, off, 64);
      const int   k2 = __shfl_xor(ki, off, 64);
      if (v2 < v || (v2 == v && k2 < ki)) { v = v2; ki = k2; }
    }
    if (lane == 0) { rbest[w][r0 + r] = v; rbidx[w][r0 + r] = ki; }
  }
  __syncthreads();

  // Merge the two code halves per row (ws=0 then ws=1; strict < keeps lowest k).
  if (tid < 16) {
    const int w0 = (tid >> 3) << 1;    // wave with ws=0 for this row's half
    float bb = rbest[w0][tid];
    int   bi = rbidx[w0][tid];
    const float v1 = rbest[w0 + 1][tid];
    if (v1 < bb) { bb = v1; bi = rbidx[w0 + 1][tid]; }
    idxout[n0 + tid] = bi;
    out[IDX_OFF + n0 + tid] = (float)bi;       // fp32 index output
  }
}

// K2: gather codebook rows per block into LDS, write x_q_st (fp32), accumulate loss.
// Overwrites ALL of out's x_q region (including the cbT scratch area).
__global__ __launch_bounds__(256, 2)
void vq_gather_kernel(const float* __restrict__ x, const float* __restrict__ cb,
                      const int* __restrict__ idxin, float* __restrict__ loss_acc,
                      float* __restrict__ out) {
  __shared__ float qs[64][260];
  __shared__ int   idx_s[64];
  __shared__ float wr[4];

  const int tid  = threadIdx.x;
  const int lane = tid & 63;
  const int w    = tid >> 6;
  const int n0   = blockIdx.x << 6;
  const int b    = n0 >> 10;
  const int hw0  = n0 & 1023;

  if (tid < 64) idx_s[tid] = idxin[n0 + tid];
  __syncthreads();

  const float4* __restrict__ cb4 = (const float4*)cb;
  for (int r = w; r < 64; r += 4) {
    const int c = idx_s[r];
    const float4 v = cb4[((size_t)c << 6) + lane];  // coalesced 1KB row read per wave
    *(float4*)&qs[r][lane << 2] = v;
  }
  __syncthreads();

  float lsum = 0.f;
  const size_t obase = (size_t)b * (DD * HWC) + hw0 + lane;
  for (int i = 0; i < 64; ++i) {
    const int d = (w << 6) + i;
    const size_t o = obase + (size_t)d * HWC;
    const float q  = qs[lane][d];
    const float xv = x[o];
    {
#pragma clang fp contract(off)
      const float df = q - xv;           // fl(x_q - x)
      out[o] = xv + df;                  // x_q_st = fl(x + fl(x_q - x)), fp32
      lsum = fmaf(df, df, lsum);         // loss accumulation (loose threshold)
    }
  }

  for (int off = 32; off > 0; off >>= 1) lsum += __shfl_down(lsum, off, 64);
  if (lane == 0) wr[w] = lsum;
  __syncthreads();
  if (tid == 0) atomicAdd(loss_acc, (wr[0] + wr[1]) + (wr[2] + wr[3]));
}

// K3: loss = 1.5 * mean((x_q - x)^2), fp32
__global__ void vq_loss_kernel(const float* __restrict__ loss_acc,
                               float* __restrict__ out) {
  if (threadIdx.x == 0) {
    const float m = loss_acc[0] / 8388608.0f;
    out[LOSS_OFF] = m + 0.5f * m;
  }
}

extern "C" void kernel_launch(void* const* d_in, const int* in_sizes, int n_in,
                              void* d_out, int out_size, void* d_ws, size_t ws_size,
                              hipStream_t stream) {
  const float* x  = (const float*)d_in[0];   // [32,256,32,32] fp32
  const float* cb = (const float*)d_in[1];   // [1024,256] fp32
  float* out = (float*)d_out;                // [x_q_st | loss | indices] fp32

  float* esq      = (float*)d_ws;            // 1024 floats
  float* loss_acc = esq + 1024;              // 1 float (zeroed by K0 each call)
  int*   idxbuf   = (int*)(esq + 1040);      // 32768 ints
  float* cbT      = out + CBT_OFF;           // 256x1024 floats, overwritten by K2

  hipLaunchKernelGGL(vq_esq_kernel,       dim3(4),    dim3(256), 0, stream, cb, esq, loss_acc);
  hipLaunchKernelGGL(vq_transpose_kernel, dim3(256),  dim3(256), 0, stream, cb, cbT);
  hipLaunchKernelGGL(vq_argmin_kernel,    dim3(2048), dim3(256), 0, stream, x, cbT, esq, idxbuf, out);
  hipLaunchKernelGGL(vq_gather_kernel,    dim3(512),  dim3(256), 0, stream, x, cb, idxbuf, loss_acc, out);
  hipLaunchKernelGGL(vq_loss_kernel,      dim3(1),    dim3(64),  0, stream, loss_acc, out);
}

// Round 16
// 215.566 us; speedup vs baseline: 1.2078x; 1.2078x over previous
//
#include <hip/hip_runtime.h>
#include <hip/hip_bf16.h>

#define KC   1024
#define DD   256
#define NN   32768
#define HWC  1024
#define LOSS_OFF 8388608
#define IDX_OFF  8388609
#define CBT_OFF  2000000   // cbT[256][1024] in out's x_q region; gather overwrites later

// Replicate numpy pairwise_sum of a[i]*a[i], n=256 (validated: absmax 0.0 r2..r15).
__device__ __forceinline__ float np_pairwise_sumsq_256(const float* __restrict__ a) {
#pragma clang fp contract(off)
  float half0, half1;
  {
    const float* p = a;
    float r[8];
#pragma unroll
    for (int j = 0; j < 8; ++j) r[j] = p[j] * p[j];
    for (int i = 8; i < 128; i += 8) {
#pragma unroll
      for (int j = 0; j < 8; ++j) r[j] = r[j] + p[i + j] * p[i + j];
    }
    half0 = ((r[0] + r[1]) + (r[2] + r[3])) + ((r[4] + r[5]) + (r[6] + r[7]));
  }
  {
    const float* p = a + 128;
    float r[8];
#pragma unroll
    for (int j = 0; j < 8; ++j) r[j] = p[j] * p[j];
    for (int i = 8; i < 128; i += 8) {
#pragma unroll
      for (int j = 0; j < 8; ++j) r[j] = r[j] + p[i + j] * p[i + j];
    }
    half1 = ((r[0] + r[1]) + (r[2] + r[3])) + ((r[4] + r[5]) + (r[6] + r[7]));
  }
  return half0 + half1;
}

// K0: e_sq[k] via numpy-pairwise; zero loss accumulator.
__global__ void vq_esq_kernel(const float* __restrict__ cb, float* __restrict__ esq,
                              float* __restrict__ loss_acc) {
  const int k = blockIdx.x * 256 + threadIdx.x;
  if (k == 0) loss_acc[0] = 0.0f;
  if (k < KC) esq[k] = np_pairwise_sumsq_256(cb + ((size_t)k << 8));
}

// K0b: cbT[d][k] = cb[k][d] (1MB, L2-resident; makes argmin e-loads coalesced).
__global__ __launch_bounds__(256) void vq_transpose_kernel(const float* __restrict__ cb,
                                                           float* __restrict__ cbT) {
  const int d = blockIdx.x;     // 0..255
  const int t = threadIdx.x;
#pragma unroll
  for (int q = 0; q < 4; ++q) {
    const int k = (q << 8) + t;
    cbT[(d << 10) + k] = cb[((size_t)k << 8) + d];
  }
}

// K1: fused distance + argmin — r13's validated structure with 16 ROWS/THREAD
// (block = 32 rows, grid 1024). Per 4-dim chunk: same 8 e-loads + 4 x s_loads
// but 512 FMA instrs = 1024 cyc of issue — double the latency-cover window
// per load group (r14's regression isolated short FMA blocks as the cost;
// r15 showed explicit prefetch only burns occupancy — compiler already
// pipelines). acc[8][16]=128 VGPR; live ~175 << 256 budget at LB(256,2).
//   wave w: ws=w&1 -> code half [ws*512,+512); rh=w>>1 -> rows rh*16..+16
//   thread: 8 contiguous codes c0 = ws*512 + lane*8 (ascending j = ascending k)
// Chain order per acc: dims ascending, chunk-major — identical to r13.
__global__ __launch_bounds__(256, 2)
void vq_argmin_kernel(const float* __restrict__ x, const float* __restrict__ cbT,
                      const float* __restrict__ esq, int* __restrict__ idxout,
                      float* __restrict__ out) {
  __shared__ float xs[32][260];    // 32 rows x 256 d (for xsq only)
  __shared__ float xsq[32];
  __shared__ float rbest[4][32];
  __shared__ int   rbidx[4][32];

  const int tid  = threadIdx.x;
  const int lane = tid & 63;
  const int w    = __builtin_amdgcn_readfirstlane(tid >> 6);  // 0..3, SGPR
  const int ws   = w & 1;             // code half
  const int rh   = w >> 1;            // row half
  const int n0   = blockIdx.x << 5;   // 1024 blocks x 32 rows
  const int b    = n0 >> 10;
  const int hw0  = n0 & 1023;
  const float* __restrict__ xb = x + (size_t)b * (DD * HWC) + hw0;

  // Stage x tile for xsq: xs[r][d] = x[b, d, hw0+r]; 32-lane contiguous reads.
  {
    const int rr = tid & 31;
    const int dq = tid >> 5;          // 0..7
#pragma unroll
    for (int i = 0; i < 32; ++i) {
      const int d = (i << 3) + dq;
      xs[rr][d] = xb[(size_t)d * HWC + rr];
    }
  }
  __syncthreads();

  // x_sq per row, numpy-pairwise bitwise (tie reproduction — do not change).
  if (tid < 32) xsq[tid] = np_pairwise_sumsq_256(&xs[tid][0]);
  __syncthreads();

  const int c0 = (ws << 9) + (lane << 3);          // 8 contiguous codes
  const int r0 = rh << 4;                          // 16 rows (uniform: w is SGPR)
  const float* __restrict__ xru = xb + r0;         // wave-uniform base

  float acc[8][16];                                // [code j][row r]
#pragma unroll
  for (int j = 0; j < 8; ++j)
#pragma unroll
    for (int r = 0; r < 16; ++r) acc[j][r] = 0.0f;

  // 64 chunks x 4 dims. Per chunk: 8 coalesced e-loads (VGPR) + 4 wave-uniform
  // x s_loads (dwordx16, SGPR) + 512 FMA instrs (1024 cyc). Single-buffered;
  // compiler pipelines (r15 lesson).
  for (int ch = 0; ch < 64; ++ch) {
    const int dbase = ch << 2;

    // x: XA[di][r] = x[b][dbase+di][hw0+r0+r], 16 contiguous floats per dim.
    float xa[4][16];
#pragma unroll
    for (int di = 0; di < 4; ++di) {
      const float* __restrict__ rp = xru + (size_t)(dbase + di) * HWC;
#pragma unroll
      for (int r = 0; r < 16; ++r) xa[di][r] = rp[r];
    }

    // e: ee[di][j] = cbT[dbase+di][c0+j], coalesced float4 pairs.
    float ee[4][8];
#pragma unroll
    for (int di = 0; di < 4; ++di) {
      const float* __restrict__ rp = cbT + ((size_t)(dbase + di) << 10) + c0;
      const float4 a = *(const float4*)rp;
      const float4 bq = *(const float4*)(rp + 4);
      ee[di][0] = a.x;  ee[di][1] = a.y;  ee[di][2] = a.z;  ee[di][3] = a.w;
      ee[di][4] = bq.x; ee[di][5] = bq.y; ee[di][6] = bq.z; ee[di][7] = bq.w;
    }

    // Per-acc chain: dims ascending (di 0..3) — identical order to r13.
#pragma unroll
    for (int r = 0; r < 16; ++r)
#pragma unroll
      for (int j = 0; j < 8; ++j)
#pragma unroll
        for (int di = 0; di < 4; ++di)
          acc[j][r] = fmaf(xa[di][r], ee[di][j], acc[j][r]);
  }

  // esq for 8 contiguous codes: two float4 loads.
  float eq[8];
  {
    const float4 e0 = *(const float4*)(esq + c0);
    const float4 e1 = *(const float4*)(esq + c0 + 4);
    eq[0]=e0.x; eq[1]=e0.y; eq[2]=e0.z; eq[3]=e0.w;
    eq[4]=e1.x; eq[5]=e1.y; eq[6]=e1.z; eq[7]=e1.w;
  }

#pragma unroll
  for (int r = 0; r < 16; ++r) {
    const float xq = xsq[r0 + r];
    float v; int ki;
    {
      // Reference rounding: fl(e_sq - fl(2*dot)) then fl(t + x_sq). No FMA here.
#pragma clang fp contract(off)
      v = (eq[0] - 2.0f * acc[0][r]) + xq; ki = c0;   // ascending j, strict <
#pragma unroll
      for (int j = 1; j < 8; ++j) {
        const float dj = (eq[j] - 2.0f * acc[j][r]) + xq;
        if (dj < v) { v = dj; ki = c0 + j; }
      }
    }
    // Wave-wide (val,idx) min, lowest k on ties.
#pragma unroll
    for (int off = 32; off >= 1; off >>= 1) {
      const float v2 = __shfl_xor(v, off, 64);
      const int   k2 = __shfl_xor(ki, off, 64);
      if (v2 < v || (v2 == v && k2 < ki)) { v = v2; ki = k2; }
    }
    if (lane == 0) { rbest[w][r0 + r] = v; rbidx[w][r0 + r] = ki; }
  }
  __syncthreads();

  // Merge the two code halves per row (ws=0 then ws=1; strict < keeps lowest k).
  if (tid < 32) {
    const int w0 = (tid >> 4) << 1;    // wave with ws=0 for this row's half
    float bb = rbest[w0][tid];
    int   bi = rbidx[w0][tid];
    const float v1 = rbest[w0 + 1][tid];
    if (v1 < bb) { bb = v1; bi = rbidx[w0 + 1][tid]; }
    idxout[n0 + tid] = bi;
    out[IDX_OFF + n0 + tid] = (float)bi;       // fp32 index output
  }
}

// K2: gather codebook rows per block into LDS, write x_q_st (fp32), accumulate loss.
// Overwrites ALL of out's x_q region (including the cbT scratch area).
__global__ __launch_bounds__(256, 2)
void vq_gather_kernel(const float* __restrict__ x, const float* __restrict__ cb,
                      const int* __restrict__ idxin, float* __restrict__ loss_acc,
                      float* __restrict__ out) {
  __shared__ float qs[64][260];
  __shared__ int   idx_s[64];
  __shared__ float wr[4];

  const int tid  = threadIdx.x;
  const int lane = tid & 63;
  const int w    = tid >> 6;
  const int n0   = blockIdx.x << 6;
  const int b    = n0 >> 10;
  const int hw0  = n0 & 1023;

  if (tid < 64) idx_s[tid] = idxin[n0 + tid];
  __syncthreads();

  const float4* __restrict__ cb4 = (const float4*)cb;
  for (int r = w; r < 64; r += 4) {
    const int c = idx_s[r];
    const float4 v = cb4[((size_t)c << 6) + lane];  // coalesced 1KB row read per wave
    *(float4*)&qs[r][lane << 2] = v;
  }
  __syncthreads();

  float lsum = 0.f;
  const size_t obase = (size_t)b * (DD * HWC) + hw0 + lane;
  for (int i = 0; i < 64; ++i) {
    const int d = (w << 6) + i;
    const size_t o = obase + (size_t)d * HWC;
    const float q  = qs[lane][d];
    const float xv = x[o];
    {
#pragma clang fp contract(off)
      const float df = q - xv;           // fl(x_q - x)
      out[o] = xv + df;                  // x_q_st = fl(x + fl(x_q - x)), fp32
      lsum = fmaf(df, df, lsum);         // loss accumulation (loose threshold)
    }
  }

  for (int off = 32; off > 0; off >>= 1) lsum += __shfl_down(lsum, off, 64);
  if (lane == 0) wr[w] = lsum;
  __syncthreads();
  if (tid == 0) atomicAdd(loss_acc, (wr[0] + wr[1]) + (wr[2] + wr[3]));
}

// K3: loss = 1.5 * mean((x_q - x)^2), fp32
__global__ void vq_loss_kernel(const float* __restrict__ loss_acc,
                               float* __restrict__ out) {
  if (threadIdx.x == 0) {
    const float m = loss_acc[0] / 8388608.0f;
    out[LOSS_OFF] = m + 0.5f * m;
  }
}

extern "C" void kernel_launch(void* const* d_in, const int* in_sizes, int n_in,
                              void* d_out, int out_size, void* d_ws, size_t ws_size,
                              hipStream_t stream) {
  const float* x  = (const float*)d_in[0];   // [32,256,32,32] fp32
  const float* cb = (const float*)d_in[1];   // [1024,256] fp32
  float* out = (float*)d_out;                // [x_q_st | loss | indices] fp32

  float* esq      = (float*)d_ws;            // 1024 floats
  float* loss_acc = esq + 1024;              // 1 float (zeroed by K0 each call)
  int*   idxbuf   = (int*)(esq + 1040);      // 32768 ints
  float* cbT      = out + CBT_OFF;           // 256x1024 floats, overwritten by K2

  hipLaunchKernelGGL(vq_esq_kernel,       dim3(4),    dim3(256), 0, stream, cb, esq, loss_acc);
  hipLaunchKernelGGL(vq_transpose_kernel, dim3(256),  dim3(256), 0, stream, cb, cbT);
  hipLaunchKernelGGL(vq_argmin_kernel,    dim3(1024), dim3(256), 0, stream, x, cbT, esq, idxbuf, out);
  hipLaunchKernelGGL(vq_gather_kernel,    dim3(512),  dim3(256), 0, stream, x, cb, idxbuf, loss_acc, out);
  hipLaunchKernelGGL(vq_loss_kernel,      dim3(1),    dim3(64),  0, stream, loss_acc, out);
}